// Round 8
// baseline (147.033 us; speedup 1.0000x reference)
//
#include <hip/hip_runtime.h>

// ---------- types ----------
using bf16x8 = __attribute__((ext_vector_type(8))) __bf16;
using f32x4  = __attribute__((ext_vector_type(4))) float;
using f32x2  = __attribute__((ext_vector_type(2))) float;
using us8    = __attribute__((ext_vector_type(8))) unsigned short;

#define TWO_LOG2E 2.8853900817779268f
#define LOG2E 1.4426950408889634f

__device__ __forceinline__ unsigned short f2bf(float x) {
  unsigned int u = __float_as_uint(x);
  u = (u + 0x7fffu + ((u >> 16) & 1u)) >> 16;   // RNE
  return (unsigned short)u;
}
__device__ __forceinline__ float bf2f(unsigned short h) {
  return __uint_as_float(((unsigned int)h) << 16);
}

// ---------- 1) tiled transpose+cast W/V + wv prologue + LPT job table ----------
__global__ __launch_bounds__(256) void tcast_kernel(
    const float* __restrict__ Wq, const float* __restrict__ Wk,
    const float* __restrict__ vals, const float* __restrict__ wv,
    const int* __restrict__ vlens,
    unsigned short* __restrict__ wt_hi, unsigned short* __restrict__ wt_lo,
    unsigned short* __restrict__ vt_hi, unsigned short* __restrict__ vt_lo,
    float* __restrict__ wv2, float* __restrict__ Wsum,
    unsigned short* __restrict__ jobs, int* __restrict__ ctr) {
  if (blockIdx.x == 0) {
    int t = threadIdx.x;
    wv2[t] = -2.0f * wv[t];                       // folded weight for scores
    if (t < 64) {
      float s = wv[t] + wv[t + 64] + wv[t + 128] + wv[t + 192];
#pragma unroll
      for (int off = 1; off < 64; off <<= 1) s += __shfl_xor(s, off, 64);
      if (t == 0) Wsum[0] = s;
    }
    if (t == 0) {                                 // LPT job table: heavy vl first
      ctr[0] = 0;
      int n = 0;
      for (int lvl = 4; lvl >= 1; --lvl)
        for (int b = 0; b < 16; ++b) {
          int kt = (vlens[b] + 63) >> 6;          // 1..4 k64-tiles
          if (kt == lvl)
            for (int q = 0; q < 32; ++q)
              jobs[n++] = (unsigned short)((b << 5) | q);   // (b, q8-strip)
        }
    }
  }
  __shared__ float tile[32][33];
  int m = blockIdx.x >> 6;                 // matrix 0..17
  int ts = blockIdx.x & 63;
  int R0 = (ts >> 3) << 5, C0 = (ts & 7) << 5;
  const float* src = (m == 0) ? Wq : (m == 1) ? Wk : (vals + ((m - 2) << 16));
  int r = threadIdx.x >> 3, c4 = (threadIdx.x & 7) << 2;
  float4 v = *(const float4*)(src + (R0 + r) * 256 + C0 + c4);
  tile[r][c4] = v.x; tile[r][c4 + 1] = v.y; tile[r][c4 + 2] = v.z; tile[r][c4 + 3] = v.w;
  __syncthreads();
  float o0 = tile[c4 + 0][r], o1 = tile[c4 + 1][r];
  float o2 = tile[c4 + 2][r], o3 = tile[c4 + 3][r];
  unsigned short h0 = f2bf(o0), h1 = f2bf(o1), h2 = f2bf(o2), h3 = f2bf(o3);
  int base = ((m < 2) ? (m << 16) : ((m - 2) << 16)) + (C0 + r) * 256 + R0 + c4;
  unsigned short* dh = (m < 2) ? wt_hi : vt_hi;
  unsigned short* dl = (m < 2) ? wt_lo : vt_lo;
  *(ushort4*)(dh + base) = make_ushort4(h0, h1, h2, h3);
  *(ushort4*)(dl + base) = make_ushort4(f2bf(o0 - bf2f(h0)), f2bf(o1 - bf2f(h1)),
                                        f2bf(o2 - bf2f(h2)), f2bf(o3 - bf2f(h3)));
}

// ---------- 2) projection GEMM + R = e^{2x} epilogue ----------
// Invalid k-tiles (rows >= valid_len) zero-fill RkT so sav5 reads unguarded.
__global__ __launch_bounds__(256, 4) void proj_kernel(
    const float* __restrict__ q, const float* __restrict__ kk,
    const unsigned short* __restrict__ w_hi, const unsigned short* __restrict__ w_lo,
    const int* __restrict__ vlens, float* __restrict__ Rq, float* __restrict__ RkT) {
  int wave = threadIdx.x >> 6, lane = threadIdx.x & 63;
  int mt = (blockIdx.x << 1) + (wave & 1);   // m-tile 0..511
  int m0 = mt << 4;
  int g = mt >> 8;                           // 0: q rows / W_q, 1: k rows / W_k
  int r = lane & 15, qd = lane >> 4;
  int nbase = (blockIdx.y << 6) + ((wave >> 1) << 5);
  if (g) {
    int bb = (m0 >> 8) & 15;
    if ((m0 & 255) >= vlens[bb]) {           // dead tile: write zeros, no GEMM
      f32x4 z = {0.f, 0.f, 0.f, 0.f};
      int kloc = (m0 & 255) + qd * 4;
#pragma unroll
      for (int tI = 0; tI < 2; ++tI)
        *(f32x4*)(RkT + (bb << 16) + (nbase + (tI << 4) + r) * 256 + kloc) = z;
      return;
    }
  }
  int row = m0 + r;
  const float* A = (g == 0) ? (q + row * 256) : (kk + (row - 4096) * 256);
  int boff0 = (g << 16) + (nbase + r) * 256 + qd * 8;
  int boff1 = boff0 + (16 << 8);             // second n-tile (+16 rows)
  f32x4 acc0 = {0.f, 0.f, 0.f, 0.f}, acc1 = {0.f, 0.f, 0.f, 0.f};
#pragma unroll
  for (int kh = 0; kh < 2; ++kh) {
    bf16x8 ah[4], al[4];
#pragma unroll
    for (int s = 0; s < 4; ++s) {
      const float* p = A + qd * 8 + (kh * 4 + s) * 32;
      float4 f0 = *(const float4*)p;
      float4 f1 = *(const float4*)(p + 4);
      float fv[8] = {f0.x, f0.y, f0.z, f0.w, f1.x, f1.y, f1.z, f1.w};
#pragma unroll
      for (int j = 0; j < 8; ++j) {
        __bf16 h = (__bf16)fv[j];
        ah[s][j] = h;
        al[s][j] = (__bf16)(fv[j] - (float)h);
      }
    }
#pragma unroll
    for (int s = 0; s < 4; ++s) {
      int off = (kh * 4 + s) * 32;
      bf16x8 bh0 = *(const bf16x8*)(w_hi + boff0 + off);
      bf16x8 bl0 = *(const bf16x8*)(w_lo + boff0 + off);
      acc0 = __builtin_amdgcn_mfma_f32_16x16x32_bf16(ah[s], bh0, acc0, 0, 0, 0);
      acc0 = __builtin_amdgcn_mfma_f32_16x16x32_bf16(ah[s], bl0, acc0, 0, 0, 0);
      acc0 = __builtin_amdgcn_mfma_f32_16x16x32_bf16(al[s], bh0, acc0, 0, 0, 0);
      bf16x8 bh1 = *(const bf16x8*)(w_hi + boff1 + off);
      bf16x8 bl1 = *(const bf16x8*)(w_lo + boff1 + off);
      acc1 = __builtin_amdgcn_mfma_f32_16x16x32_bf16(ah[s], bh1, acc1, 0, 0, 0);
      acc1 = __builtin_amdgcn_mfma_f32_16x16x32_bf16(ah[s], bl1, acc1, 0, 0, 0);
      acc1 = __builtin_amdgcn_mfma_f32_16x16x32_bf16(al[s], bh1, acc1, 0, 0, 0);
    }
  }
#pragma unroll
  for (int tI = 0; tI < 2; ++tI) {
    f32x4 acc = tI ? acc1 : acc0;
    int n0 = nbase + (tI << 4);
    f32x4 ex;
#pragma unroll
    for (int i = 0; i < 4; ++i) {
      float l = acc[i] * TWO_LOG2E;                 // log2(e^{2x})
      l = fminf(fmaxf(l, -27.f), 27.f);
      ex[i] = __builtin_amdgcn_exp2f(l);
    }
    if (g == 0) {
#pragma unroll
      for (int i = 0; i < 4; ++i)
        Rq[(m0 + qd * 4 + i) * 256 + n0 + r] = ex[i];
    } else {
      int b = (m0 >> 8) & 15;
      int kloc = (m0 & 255) + qd * 4;               // contiguous in i
      *(f32x4*)(RkT + (b << 16) + (n0 + r) * 256 + kloc) = ex;
    }
  }
}

// ---------- 3) sav5: R6 skeleton + 2-row-amortized LDS-light scores ----------
// 256 blocks x 512 thr, LPT steal (all as passing R6). Change vs R6: the full
// [256h][128k] K-panel staged once (stride 132), wave w computes q-pair
// (2(w&3), 2(w&3)+1) x k-subtile (w>>2): 1 kT read + 0.75 broadcast per h for
// TWO rows = 3.4x less LDS traffic per (q,k,h) op. Same FMA/rcp chain/order.
__global__ __launch_bounds__(512) void sav5_kernel(
    const float* __restrict__ Rq, const float* __restrict__ RkT,
    const float* __restrict__ wv2, const float* __restrict__ Wsum,
    const int* __restrict__ vlens, const unsigned short* __restrict__ jobs,
    int* __restrict__ ctr,
    const unsigned short* __restrict__ vhi, const unsigned short* __restrict__ vlo,
    float* __restrict__ out) {
  __shared__ __align__(16) float kTm[256 * 132];   // [h][128k] pad->132 (staging 4-way max)
  __shared__ __align__(16) float rqs[8 * 260];     // [q8][h]
  __shared__ __align__(16) float scs[8 * 264];     // [q8][k]
  __shared__ __align__(16) unsigned short athi[16 * 264];  // rows 8..15 stay 0
  __shared__ __align__(16) float wv2s[256];
  __shared__ int s_item;
  const int t = threadIdx.x;
  const int w = t >> 6, lane = t & 63;
  const float wsum = Wsum[0];

  if (t < 256) wv2s[t] = wv2[t];
  for (int i = t; i < 8 * 264; i += 512) athi[8 * 264 + i] = 0;  // zero A top half

  const int ql  = (w & 3) << 1;        // q-row pair this wave computes
  const int ktl = w >> 2;              // k-subtile (0/1) within the mega-panel
  const int kloc = (ktl << 6) + lane;  // 0..127 within panel

  for (;;) {
    __syncthreads();                    // prev job's LDS reads done; init visible
    if (t == 0) s_item = atomicAdd(ctr, 1);
    __syncthreads();
    const int jid = s_item;
    if (jid >= 512) return;             // uniform exit
    const int jw = jobs[jid];
    const int b = jw >> 5, q0 = (jw & 31) << 3;
    const int qrow = (b << 8) + q0;
    const int vl = vlens[b];
    const int kt64 = (vl + 63) >> 6;    // 1..4
    const int nmega = (kt64 + 1) >> 1;  // 1..2 128-wide K panels

    { // stage rqs 8x256 (each thread one float4, coalesced)
      int row = t >> 6, c = lane << 2;
      *(float4*)(rqs + row * 260 + c) = *(const float4*)(Rq + (qrow + row) * 256 + c);
    }

    for (int m = 0; m < nmega; ++m) {
      __syncthreads();                  // prev panel compute done / rqs staged
      { // stage K panel [256h][128k] from RkT[b][h][m*128+*] (zero-filled -> safe)
        int hh = t >> 3, kc = (t & 7) << 4;
#pragma unroll
        for (int p = 0; p < 4; ++p) {
          int h = (p << 6) + hh;
          const float* gk = RkT + (b << 16) + h * 256 + (m << 7) + kc;
          float* dst = kTm + h * 132 + kc;
          *(float4*)(dst)      = *(const float4*)(gk);
          *(float4*)(dst + 4)  = *(const float4*)(gk + 4);
          *(float4*)(dst + 8)  = *(const float4*)(gk + 8);
          *(float4*)(dst + 12) = *(const float4*)(gk + 12);
        }
      }
      __syncthreads();
      const int tiles = kt64 - (m << 1);          // #valid 64-subtiles this panel
      if (ktl < tiles) {
        const float* kp = kTm + kloc;             // + h*132, row-contiguous read
        const float* qa0 = rqs + ql * 260;
        const float* qa1 = qa0 + 260;
        float acc0 = 0.f, acc1 = 0.f;
#pragma unroll 2
        for (int h = 0; h < 256; h += 4) {
          f32x4 wa = *(const f32x4*)(wv2s + h);   // broadcast b128
          f32x4 a0 = *(const f32x4*)(qa0 + h);    // broadcast b128
          f32x4 a1 = *(const f32x4*)(qa1 + h);    // broadcast b128
#pragma unroll
          for (int j = 0; j < 4; ++j) {
            float rk = kp[(h + j) * 132];         // per-lane b32, conflict-free
            float d0 = __builtin_fmaf(rk, a0[j], 1.0f);
            float d1 = __builtin_fmaf(rk, a1[j], 1.0f);
            acc0 = __builtin_fmaf(__builtin_amdgcn_rcpf(d0), wa[j], acc0);
            acc1 = __builtin_fmaf(__builtin_amdgcn_rcpf(d1), wa[j], acc1);
          }
        }
        const int kg = (m << 7) + kloc;
        scs[ql * 264 + kg]       = acc0 + wsum;
        scs[(ql + 1) * 264 + kg] = acc1 + wsum;
      }
    }
    __syncthreads();                    // all scores written

    { // masked softmax: wave w owns row w; lane covers 4 cols (R6 verbatim)
      int c0 = lane << 2;
      float4 x = *(const float4*)(scs + w * 264 + c0);
      float p[4] = {x.x, x.y, x.z, x.w};
#pragma unroll
      for (int i = 0; i < 4; ++i)
        if (c0 + i >= vl) p[i] = -1e6f;       // covers never-computed cols too
      float mx = fmaxf(fmaxf(p[0], p[1]), fmaxf(p[2], p[3]));
#pragma unroll
      for (int off = 1; off < 64; off <<= 1) mx = fmaxf(mx, __shfl_xor(mx, off, 64));
      float sm = 0.f;
#pragma unroll
      for (int i = 0; i < 4; ++i) {
        p[i] = __builtin_amdgcn_exp2f((p[i] - mx) * LOG2E);   // masked -> 0
        sm += p[i];
      }
#pragma unroll
      for (int off = 1; off < 64; off <<= 1) sm += __shfl_xor(sm, off, 64);
      float rs = __builtin_amdgcn_rcpf(sm);
      ushort4 vh;
      vh.x = f2bf(p[0] * rs); vh.y = f2bf(p[1] * rs);
      vh.z = f2bf(p[2] * rs); vh.w = f2bf(p[3] * rs);
      *(ushort4*)(athi + w * 264 + c0) = vh;
    }
    __syncthreads();

    { // AV: wave w -> n in [32w, 32w+32); A rows 0..7 valid (R6 verbatim)
      const int r = lane & 15, qd = lane >> 4;
      const int smax = (vl + 31) >> 5;
      const int nb = w << 5;
      const int boff = (b << 16) + (nb + r) * 256 + qd * 8;
      f32x4 acc0 = {0.f, 0.f, 0.f, 0.f}, acc1 = {0.f, 0.f, 0.f, 0.f};
      for (int s = 0; s < smax; ++s) {
        bf16x8 pa = *(const bf16x8*)(athi + r * 264 + qd * 8 + s * 32);
        bf16x8 bh0 = *(const bf16x8*)(vhi + boff + s * 32);
        bf16x8 bl0 = *(const bf16x8*)(vlo + boff + s * 32);
        acc0 = __builtin_amdgcn_mfma_f32_16x16x32_bf16(pa, bh0, acc0, 0, 0, 0);
        acc0 = __builtin_amdgcn_mfma_f32_16x16x32_bf16(pa, bl0, acc0, 0, 0, 0);
        bf16x8 bh1 = *(const bf16x8*)(vhi + boff + (16 << 8) + s * 32);
        bf16x8 bl1 = *(const bf16x8*)(vlo + boff + (16 << 8) + s * 32);
        acc1 = __builtin_amdgcn_mfma_f32_16x16x32_bf16(pa, bh1, acc1, 0, 0, 0);
        acc1 = __builtin_amdgcn_mfma_f32_16x16x32_bf16(pa, bl1, acc1, 0, 0, 0);
      }
      if (qd < 2) {                      // only D rows 0..7 are real q-rows
#pragma unroll
        for (int i = 0; i < 4; ++i) {
          out[(b << 16) + (q0 + qd * 4 + i) * 256 + nb + r]      = acc0[i];
          out[(b << 16) + (q0 + qd * 4 + i) * 256 + nb + 16 + r] = acc1[i];
        }
      }
    }
  }
}

extern "C" void kernel_launch(void* const* d_in, const int* in_sizes, int n_in,
                              void* d_out, int out_size, void* d_ws, size_t ws_size,
                              hipStream_t stream) {
  const float* queries = (const float*)d_in[0];
  const float* keys    = (const float*)d_in[1];
  const float* values  = (const float*)d_in[2];
  const int*   vlens   = (const int*)d_in[3];
  const float* Wq      = (const float*)d_in[4];
  const float* Wk      = (const float*)d_in[5];
  const float* wv      = (const float*)d_in[6];
  float* out = (float*)d_out;
  char* ws = (char*)d_ws;

  // workspace layout (bytes), ~13.3 MB
  unsigned short* wt_hi = (unsigned short*)(ws + 0);          // 256 KB
  unsigned short* wt_lo = (unsigned short*)(ws + 262144);     // 256 KB
  unsigned short* vt_hi = (unsigned short*)(ws + 524288);     //   2 MB
  unsigned short* vt_lo = (unsigned short*)(ws + 2621440);    //   2 MB
  float*          Rq    = (float*)(ws + 4718592);             //   4 MB [q][h]
  float*          RkT   = (float*)(ws + 8912896);             //   4 MB [b][h][k]
  float*          wv2   = (float*)(ws + 13107200);            //   1 KB
  float*          Wsum  = (float*)(ws + 13108224);            //   4 B
  unsigned short* jobs  = (unsigned short*)(ws + 13109248);   //   1 KB (512 jobs)
  int*            ctr   = (int*)(ws + 13110272);              //   4 B (zeroed by tcast)

  tcast_kernel<<<1152, 256, 0, stream>>>(Wq, Wk, values, wv, vlens,
                                         wt_hi, wt_lo, vt_hi, vt_lo, wv2, Wsum,
                                         jobs, ctr);
  proj_kernel<<<dim3(256, 4), 256, 0, stream>>>(queries, keys, wt_hi, wt_lo,
                                                vlens, Rq, RkT);
  sav5_kernel<<<256, 512, 0, stream>>>(Rq, RkT, wv2, Wsum, vlens, jobs, ctr,
                                       vt_hi, vt_lo, out);
}